// Round 8
// baseline (163.256 us; speedup 1.0000x reference)
//
#include <hip/hip_runtime.h>
#include <math.h>

#define BB 8
#define NN 2000
#define CC 81
#define NPAD 2048
#define MAXI 100
#define HH 512
#define WW 512

// ---------------------------------------------------------------------------
// Kernel A: per-proposal class argmax, delta refine, validity, sort key.
// [R4-proven bit-exact]
// ---------------------------------------------------------------------------
__global__ void k_refine(const float* __restrict__ rois,
                         const float* __restrict__ probs,
                         const float* __restrict__ deltas,
                         const float* __restrict__ stdv,
                         float* __restrict__ score, int* __restrict__ cls,
                         int* __restrict__ valid, float* __restrict__ box,
                         unsigned long long* __restrict__ gkeys) {
#pragma clang fp contract(off)
  int g = blockIdx.x * 4 + (threadIdx.x >> 6);
  if (g >= BB * NPAD) return;
  int lane = threadIdx.x & 63;
  int b = g >> 11, n = g & (NPAD - 1);
  if (n >= NN) {                      // pad slot: sentinel key + invalid
    if (lane == 0) {
      unsigned u = __float_as_uint(-INFINITY);
      u = ~u;                         // sign set -> ~u
      gkeys[b * NPAD + n] =
          ((unsigned long long)u << 32) | (0xFFFFFFFFu - (unsigned)n);
      valid[b * NPAD + n] = 0;        // NMS gathers this slot; ws is poisoned
    }
    return;
  }
  const float* pp = probs + ((size_t)b * NN + n) * CC;
  float best = -INFINITY;
  int bc = CC;
  for (int c = lane; c < CC; c += 64) {
    float p = pp[c];
    if (p > best) { best = p; bc = c; }   // per-lane stride keeps first max
  }
  // cross-lane argmax, first-occurrence tie-break (smaller class wins)
  for (int off = 32; off; off >>= 1) {
    float ob = __shfl_xor(best, off, 64);
    int oc = __shfl_xor(bc, off, 64);
    if (ob > best || (ob == best && oc < bc)) { best = ob; bc = oc; }
  }
  if (lane == 0) {
    int idx = b * NPAD + n;
    const float* r = rois + ((size_t)b * NN + n) * 4;
    const float* dd = deltas + (((size_t)b * NN + n) * CC + bc) * 4;
    float d0 = dd[0] * stdv[0], d1 = dd[1] * stdv[1];
    float d2 = dd[2] * stdv[2], d3 = dd[3] * stdv[3];
    float y1 = r[0], x1 = r[1], y2 = r[2], x2 = r[3];
    float h = y2 - y1, w = x2 - x1;
    float cy = y1 + 0.5f * h + d0 * h;
    float cx = x1 + 0.5f * w + d1 * w;
    h = h * (float)exp((double)d2);   // double path ~= correctly-rounded f32 exp
    w = w * (float)exp((double)d3);
    float ny1 = cy - 0.5f * h, nx1 = cx - 0.5f * w;
    float ny2 = cy + 0.5f * h, nx2 = cx + 0.5f * w;
    ny1 = fminf(fmaxf(ny1, 0.f), 1.f);
    nx1 = fminf(fmaxf(nx1, 0.f), 1.f);
    ny2 = fminf(fmaxf(ny2, 0.f), 1.f);
    nx2 = fminf(fmaxf(nx2, 0.f), 1.f);
    box[idx * 4 + 0] = ny1;
    box[idx * 4 + 1] = nx1;
    box[idx * 4 + 2] = ny2;
    box[idx * 4 + 3] = nx2;
    score[idx] = best;
    cls[idx] = bc;
    int v = (bc > 0 && best >= 0.05f) ? 1 : 0;
    valid[idx] = v;
    float ks = v ? best : -INFINITY;
    unsigned u = __float_as_uint(ks);
    u = (u & 0x80000000u) ? ~u : (u | 0x80000000u);
    gkeys[idx] = ((unsigned long long)u << 32) | (0xFFFFFFFFu - (unsigned)n);
  }
}

// ---------------------------------------------------------------------------
// Kernel B: partial rank counts, CHIP-WIDE (512 blocks). [R4-proven]
// ---------------------------------------------------------------------------
__global__ void k_rankp(const unsigned long long* __restrict__ gkeys,
                        int* __restrict__ partial) {
  __shared__ unsigned long long sk[256];
  int blk = blockIdx.x;                 // b*64 + ip*8 + jp
  int jp = blk & 7, ip = (blk >> 3) & 7, b = blk >> 6;
  int tid = threadIdx.x;
  sk[tid] = gkeys[b * NPAD + jp * 256 + tid];
  unsigned long long myk = gkeys[b * NPAD + ip * 256 + tid];
  __syncthreads();
  int cnt = 0;
#pragma unroll 8
  for (int j = 0; j < 256; j++) cnt += (sk[j] > myk) ? 1 : 0;
  partial[(b * 8 + jp) * NPAD + ip * 256 + tid] = cnt;
}

// ---------------------------------------------------------------------------
// Kernel C (v7): perm + mask-based chunked greedy NMS, 1 block/batch.
// R7 lesson: the old candidate-serial loop was latency-bound (~700 cyc/cand
// of chained ds_bpermute+ballot; VALUBusy 0.19%). Suppression is MONOTONE
// (eligibility only decreases as accepts accumulate), so greedy over a
// 256-candidate chunk needs one ballot PER ACCEPT, not per candidate:
//   P1: stage 256 sorted candidates (offset box, area) in LDS, in parallel.
//   P2: each thread builds its candidate's 256-bit overlap mask vs the chunk
//       (+1 bit vs kept list) -- parallel VALU, no serial chain.
//   P3: wave 0: ok=ballot; accept lowest; lanes locally clear on conflict
//       with the new accept (own mask bit); re-ballot. ~#accept iterations.
//   P4: det/kept writes in parallel via popcount-prefix ranks.
// Greedy result identical to reference (same fp-contract-off IoU bits,
// same union order (area_row + area_col) - inter; early-exit at kept==100
// valid since list is score-sorted; per-class cap vacuous below 100 total).
// ---------------------------------------------------------------------------
__global__ void __launch_bounds__(256)
k_permnms(const int* __restrict__ partial, const float* __restrict__ score,
          const int* __restrict__ cls, const int* __restrict__ valid,
          const float* __restrict__ box, float* __restrict__ det) {
#pragma clang fp contract(off)
  __shared__ int sperm[NPAD];
  __shared__ float4 spk4[256];      // offset box (oy1,ox1,oy2,ox2)
  __shared__ float sarea[256];
  __shared__ float4 sbox4[256];     // unoffset box (for det output)
  __shared__ float sscr[256];
  __shared__ int   scl[256];
  __shared__ int   sval[256];
  __shared__ int   sksup[256];
  __shared__ unsigned long long smask[256][5];  // 4 words + pad (bank spread)
  __shared__ float4 kpk4[MAXI];     // kept offset boxes
  __shared__ float  karea[MAXI];
  __shared__ int s_kcount, s_done;

  int b = blockIdx.x, tid = threadIdx.x;
  int lane = tid & 63, wv = tid >> 6;

  // ---- phase 0: rank-sum -> permutation into LDS ----
  for (int e = tid; e < NPAD; e += 256) {
    int rank = 0;
#pragma unroll
    for (int jp = 0; jp < 8; jp++) rank += partial[(b * 8 + jp) * NPAD + e];
    sperm[rank] = e;
  }
  if (tid == 0) { s_kcount = 0; s_done = 0; }
  __syncthreads();

  int prevkept = 0;
  for (int base = 0;; base += 256) {
    // ---- phase 1: stage candidate (base+tid) ----
    {
      int i = base + tid;
      float4 bx = make_float4(0.f, 0.f, 0.f, 0.f);
      int c = 0, v = 0;
      float sc = 0.f;
      if (i < NN) {
        int o = b * NPAD + sperm[i];
        bx = ((const float4*)box)[o];
        c = cls[o]; v = valid[o]; sc = score[o];
      }
      float off = 2.0f * (float)c;
      float oy1 = bx.x + off, ox1 = bx.y + off;
      float oy2 = bx.z + off, ox2 = bx.w + off;
      float ar = (oy2 - oy1) * (ox2 - ox1);
      if (!v) { oy1 = ox1 = oy2 = ox2 = 0.f; ar = 0.f; }  // inert (never kept)
      spk4[tid] = make_float4(oy1, ox1, oy2, ox2);
      sarea[tid] = ar;
      sbox4[tid] = bx;
      sscr[tid] = sc; scl[tid] = c; sval[tid] = v;
    }
    __syncthreads();
    // ---- phase 2: kept-overlap bit + in-chunk 256-bit overlap mask ----
    {
      float4 me = spk4[tid];
      float ma = sarea[tid];
      int ks = 0;
      int kc = s_kcount;  // kept so far (previous chunks)
      for (int t = 0; t < kc; t++) {
        float4 kb = kpk4[t];
        float yy1 = fmaxf(me.x, kb.x), xx1 = fmaxf(me.y, kb.y);
        float yy2 = fminf(me.z, kb.z), xx2 = fminf(me.w, kb.w);
        float inter = fmaxf(yy2 - yy1, 0.f) * fmaxf(xx2 - xx1, 0.f);
        float uni = (ma + karea[t]) - inter;
        if (inter / fmaxf(uni, 1e-12f) > 0.3f) ks = 1;
      }
      sksup[tid] = ks;
      unsigned long long m0 = 0, m1 = 0, m2 = 0, m3 = 0;
      for (int j = 0; j < 256; j++) {
        float4 ob = spk4[j];
        float yy1 = fmaxf(me.x, ob.x), xx1 = fmaxf(me.y, ob.y);
        float yy2 = fminf(me.z, ob.z), xx2 = fminf(me.w, ob.w);
        float inter = fmaxf(yy2 - yy1, 0.f) * fmaxf(xx2 - xx1, 0.f);
        float uni = (ma + sarea[j]) - inter;
        unsigned long long bit =
            (inter / fmaxf(uni, 1e-12f) > 0.3f) ? 1ULL : 0ULL;
        if (j < 64) m0 |= bit << j;
        else if (j < 128) m1 |= bit << (j - 64);
        else if (j < 192) m2 |= bit << (j - 128);
        else m3 |= bit << (j - 192);
      }
      smask[tid][0] = m0; smask[tid][1] = m1;
      smask[tid][2] = m2; smask[tid][3] = m3;
    }
    __syncthreads();
    // ---- phase 3+4: wave 0 resolves greedily, writes det + kept ----
    if (wv == 0) {
      unsigned long long m[4][4];
      int rv[4], ok4[4];
      for (int s = 0; s < 4; s++) {
        int i = s * 64 + lane;
        m[s][0] = smask[i][0]; m[s][1] = smask[i][1];
        m[s][2] = smask[i][2]; m[s][3] = smask[i][3];
        rv[s] = sval[i];
        ok4[s] = rv[s] && !sksup[i];
      }
      unsigned long long vb0 = __ballot(rv[0] != 0);
      unsigned long long vb1 = __ballot(rv[1] != 0);
      unsigned long long vb2 = __ballot(rv[2] != 0);
      unsigned long long vb3 = __ballot(rv[3] != 0);
      bool all_valid = (vb0 & vb1 & vb2 & vb3) == ~0ULL;
      unsigned long long acc[4] = {0ULL, 0ULL, 0ULL, 0ULL};
      int kcount = prevkept;
      bool stop = false;
      for (int s = 0; s < 4 && !stop; s++) {
        bool ok = ok4[s] && (((m[s][0] & acc[0]) | (m[s][1] & acc[1]) |
                              (m[s][2] & acc[2]) | (m[s][3] & acc[3])) == 0ULL);
        unsigned long long bal = __ballot(ok);
        while (bal) {
          int o = __ffsll((unsigned long long)bal) - 1;  // lowest index wins
          acc[s] |= 1ULL << o;
          kcount++;
          if (kcount == MAXI) { stop = true; break; }
          bool conf = ((m[s][s] >> o) & 1ULL) != 0ULL;   // overlap w/ new accept
          ok = ok && !conf && (lane != o);
          bal = __ballot(ok);
        }
      }
      // deferred parallel writes: rank via popcount prefixes
      int prefix[4], run = 0;
      for (int s = 0; s < 4; s++) { prefix[s] = run; run += (int)__popcll(acc[s]); }
      for (int s = 0; s < 4; s++) {
        if ((acc[s] >> lane) & 1ULL) {
          int i = s * 64 + lane;
          int row = prevkept + prefix[s] +
                    (int)__popcll(acc[s] & ((1ULL << lane) - 1ULL));
          float4 bx = sbox4[i];
          float* dr = det + ((size_t)b * MAXI + row) * 6;
          dr[0] = bx.x; dr[1] = bx.y; dr[2] = bx.z; dr[3] = bx.w;
          dr[4] = (float)scl[i]; dr[5] = sscr[i];
          kpk4[row] = spk4[i];
          karea[row] = sarea[i];
        }
      }
      if (lane == 0) {
        s_kcount = kcount;
        s_done = (kcount >= MAXI) || !all_valid || (base + 256 >= NN) ? 1 : 0;
      }
    }
    __syncthreads();
    prevkept = s_kcount;
    if (s_done) break;   // uniform
  }
  // zero-fill remaining det rows (d_out is poisoned 0xAA)
  {
    int rem = (MAXI - prevkept) * 6;
    float* dr0 = det + ((size_t)b * MAXI + prevkept) * 6;
    for (int t = tid; t < rem; t += 256) dr0[t] = 0.f;
  }
}

// ---------------------------------------------------------------------------
// Kernel D: attention mask. One block per (batch, row); 256 threads,
// 2 pixels per thread; ballot+popcount compaction. [R4-proven bit-exact]
// ---------------------------------------------------------------------------
__global__ void k_mask(const float* __restrict__ det, float* __restrict__ mask) {
  __shared__ float lx1[MAXI], lx2[MAXI];
  __shared__ unsigned long long wmask[4];
  int x = blockIdx.x;
  int h = x & (HH - 1);
  int b = x >> 9;
  int tid = threadIdx.x;
  int wv = tid >> 6, ln = tid & 63;
  float ys = ((float)h + 0.5f) * (1.0f / 512.0f);
  bool inb = false;
  float bx1 = 0.f, bx2 = 0.f;
  if (tid < MAXI) {
    const float* dr = det + ((size_t)b * MAXI + tid) * 6;
    float y1 = dr[0], y2 = dr[2];
    bx1 = dr[1]; bx2 = dr[3];
    inb = (ys >= y1 && ys < y2);   // zero (padded) boxes cover nothing
  }
  unsigned long long bm = __ballot(inb);
  if (ln == 0) wmask[wv] = bm;
  __syncthreads();
  int n = __popcll(wmask[0]) + __popcll(wmask[1]);  // tid<100 only in waves 0,1
  if (inb) {
    int pos = (wv ? __popcll(wmask[0]) : 0) +
              __popcll(bm & ((1ULL << ln) - 1ULL));
    lx1[pos] = bx1; lx2[pos] = bx2;
  }
  __syncthreads();
  float xs0 = ((float)tid + 0.5f) * (1.0f / 512.0f);
  float xs1 = ((float)(tid + 256) + 0.5f) * (1.0f / 512.0f);
  bool c0 = false, c1 = false;
  for (int t = 0; t < n; t++) {
    float a = lx1[t], bq = lx2[t];
    c0 = c0 || (xs0 >= a && xs0 < bq);
    c1 = c1 || (xs1 >= a && xs1 < bq);
  }
  float* row = mask + ((size_t)b * HH + h) * WW;
  row[tid] = c0 ? 1.0f : 0.0f;
  row[tid + 256] = c1 ? 1.0f : 0.0f;
}

// ---------------------------------------------------------------------------
extern "C" void kernel_launch(void* const* d_in, const int* in_sizes, int n_in,
                              void* d_out, int out_size, void* d_ws, size_t ws_size,
                              hipStream_t stream) {
  const float* rois = (const float*)d_in[0];
  const float* probs = (const float*)d_in[1];
  const float* deltas = (const float*)d_in[2];
  const float* stdv = (const float*)d_in[3];
  float* out = (float*)d_out;
  float* det = out;                  // [8,100,6] = 4800 floats
  float* mask = out + BB * MAXI * 6; // [8,512,512]

  char* p = (char*)d_ws;
  unsigned long long* gkeys = (unsigned long long*)p; p += (size_t)BB * NPAD * 8;
  float* box     = (float*)p; p += (size_t)BB * NPAD * 16;
  float* score   = (float*)p; p += (size_t)BB * NPAD * 4;
  int*   cls     = (int*)p;   p += (size_t)BB * NPAD * 4;
  int*   valid   = (int*)p;   p += (size_t)BB * NPAD * 4;
  int*   partial = (int*)p;   p += (size_t)BB * 8 * NPAD * 4;

  k_refine<<<(BB * NPAD) / 4, 256, 0, stream>>>(rois, probs, deltas, stdv,
                                                score, cls, valid, box, gkeys);
  k_rankp<<<BB * 64, 256, 0, stream>>>(gkeys, partial);
  k_permnms<<<BB, 256, 0, stream>>>(partial, score, cls, valid, box, det);
  k_mask<<<BB * HH, 256, 0, stream>>>(det, mask);
}

// Round 9
// 123.531 us; speedup vs baseline: 1.3216x; 1.3216x over previous
//
#include <hip/hip_runtime.h>
#include <math.h>

#define BB 8
#define NN 2000
#define CC 81
#define NPAD 2048
#define MAXI 100
#define HH 512
#define WW 512

// ---------------------------------------------------------------------------
// Kernel A: per-proposal class argmax, delta refine, validity, sort key.
// [R4-proven bit-exact]
// ---------------------------------------------------------------------------
__global__ void k_refine(const float* __restrict__ rois,
                         const float* __restrict__ probs,
                         const float* __restrict__ deltas,
                         const float* __restrict__ stdv,
                         float* __restrict__ score, int* __restrict__ cls,
                         int* __restrict__ valid, float* __restrict__ box,
                         unsigned long long* __restrict__ gkeys) {
#pragma clang fp contract(off)
  int g = blockIdx.x * 4 + (threadIdx.x >> 6);
  if (g >= BB * NPAD) return;
  int lane = threadIdx.x & 63;
  int b = g >> 11, n = g & (NPAD - 1);
  if (n >= NN) {                      // pad slot: sentinel key + invalid
    if (lane == 0) {
      unsigned u = __float_as_uint(-INFINITY);
      u = ~u;                         // sign set -> ~u
      gkeys[b * NPAD + n] =
          ((unsigned long long)u << 32) | (0xFFFFFFFFu - (unsigned)n);
      valid[b * NPAD + n] = 0;        // NMS gathers this slot; ws is poisoned
    }
    return;
  }
  const float* pp = probs + ((size_t)b * NN + n) * CC;
  float best = -INFINITY;
  int bc = CC;
  for (int c = lane; c < CC; c += 64) {
    float p = pp[c];
    if (p > best) { best = p; bc = c; }   // per-lane stride keeps first max
  }
  // cross-lane argmax, first-occurrence tie-break (smaller class wins)
  for (int off = 32; off; off >>= 1) {
    float ob = __shfl_xor(best, off, 64);
    int oc = __shfl_xor(bc, off, 64);
    if (ob > best || (ob == best && oc < bc)) { best = ob; bc = oc; }
  }
  if (lane == 0) {
    int idx = b * NPAD + n;
    const float* r = rois + ((size_t)b * NN + n) * 4;
    const float* dd = deltas + (((size_t)b * NN + n) * CC + bc) * 4;
    float d0 = dd[0] * stdv[0], d1 = dd[1] * stdv[1];
    float d2 = dd[2] * stdv[2], d3 = dd[3] * stdv[3];
    float y1 = r[0], x1 = r[1], y2 = r[2], x2 = r[3];
    float h = y2 - y1, w = x2 - x1;
    float cy = y1 + 0.5f * h + d0 * h;
    float cx = x1 + 0.5f * w + d1 * w;
    h = h * (float)exp((double)d2);   // double path ~= correctly-rounded f32 exp
    w = w * (float)exp((double)d3);
    float ny1 = cy - 0.5f * h, nx1 = cx - 0.5f * w;
    float ny2 = cy + 0.5f * h, nx2 = cx + 0.5f * w;
    ny1 = fminf(fmaxf(ny1, 0.f), 1.f);
    nx1 = fminf(fmaxf(nx1, 0.f), 1.f);
    ny2 = fminf(fmaxf(ny2, 0.f), 1.f);
    nx2 = fminf(fmaxf(nx2, 0.f), 1.f);
    box[idx * 4 + 0] = ny1;
    box[idx * 4 + 1] = nx1;
    box[idx * 4 + 2] = ny2;
    box[idx * 4 + 3] = nx2;
    score[idx] = best;
    cls[idx] = bc;
    int v = (bc > 0 && best >= 0.05f) ? 1 : 0;
    valid[idx] = v;
    float ks = v ? best : -INFINITY;
    unsigned u = __float_as_uint(ks);
    u = (u & 0x80000000u) ? ~u : (u | 0x80000000u);
    gkeys[idx] = ((unsigned long long)u << 32) | (0xFFFFFFFFu - (unsigned)n);
  }
}

// ---------------------------------------------------------------------------
// Kernel B: partial rank counts, CHIP-WIDE (512 blocks). [R4-proven]
// ---------------------------------------------------------------------------
__global__ void k_rankp(const unsigned long long* __restrict__ gkeys,
                        int* __restrict__ partial) {
  __shared__ unsigned long long sk[256];
  int blk = blockIdx.x;                 // b*64 + ip*8 + jp
  int jp = blk & 7, ip = (blk >> 3) & 7, b = blk >> 6;
  int tid = threadIdx.x;
  sk[tid] = gkeys[b * NPAD + jp * 256 + tid];
  unsigned long long myk = gkeys[b * NPAD + ip * 256 + tid];
  __syncthreads();
  int cnt = 0;
#pragma unroll 8
  for (int j = 0; j < 256; j++) cnt += (sk[j] > myk) ? 1 : 0;
  partial[(b * 8 + jp) * NPAD + ip * 256 + tid] = cnt;
}

// ---------------------------------------------------------------------------
// Kernel C (v8): perm + mask-resolve NMS, 1 block of 1024 threads per batch.
// R8 lesson: 8-block kernels run latency-bound at a low effective clock;
// minimize SERIAL CYCLES and use 16 waves to hide memory latency.
//   P0: perm via rank-sum, 1024 threads (2 elements each).
//   P1: stage first 256 sorted candidates (offset box, area) in LDS.
//   P2: 256x256 overlap-bit matrix, thread=(row,j-word): 64 IoUs/thread,
//       independent + unrolled (was 256 serial/thread in R8).
//   P3: wave 0 greedy resolve: one ballot per ACCEPT (~100 total);
//       parallel det/kept writes via popcount-prefix ranks. [R8-proven]
//   P4: rare serial continuation past candidate 256 (R7-proven loop) iff
//       kept<100 with all 256 valid; all waves rejoin for parallel zero-fill.
// Same fp-contract-off IoU bits, union order, greedy order as reference.
// ---------------------------------------------------------------------------
__global__ void __launch_bounds__(1024)
k_permnms(const int* __restrict__ partial, const float* __restrict__ score,
          const int* __restrict__ cls, const int* __restrict__ valid,
          const float* __restrict__ box, float* __restrict__ det) {
#pragma clang fp contract(off)
  __shared__ int sperm[NPAD];
  __shared__ float4 spk4[256];      // offset box (oy1,ox1,oy2,ox2)
  __shared__ float sarea[256];
  __shared__ float4 sbox4[256];     // unoffset box (for det output)
  __shared__ float sscr[256];
  __shared__ int   scl[256];
  __shared__ int   sval[256];
  __shared__ unsigned long long smask[256][5];  // 4 words + pad
  __shared__ float4 kpk4[MAXI];     // kept offset boxes
  __shared__ float  karea[MAXI];
  __shared__ int s_kcount, s_need;

  int b = blockIdx.x, tid = threadIdx.x;
  int lane = tid & 63, wv = tid >> 6;

  // ---- P0: rank-sum -> permutation into LDS (1024 threads, 2 elems each) ----
  for (int e = tid; e < NPAD; e += 1024) {
    int rank = 0;
#pragma unroll
    for (int jp = 0; jp < 8; jp++) rank += partial[(b * 8 + jp) * NPAD + e];
    sperm[rank] = e;
  }
  if (tid == 0) { s_kcount = 0; s_need = 0; }
  __syncthreads();

  // ---- P1: stage first 256 sorted candidates ----
  if (tid < 256) {
    int o = b * NPAD + sperm[tid];
    float4 bx = ((const float4*)box)[o];
    int c = cls[o], v = valid[o];
    float sc = score[o];
    float off = 2.0f * (float)c;
    float oy1 = bx.x + off, ox1 = bx.y + off;
    float oy2 = bx.z + off, ox2 = bx.w + off;
    float ar = (oy2 - oy1) * (ox2 - ox1);
    if (!v) { oy1 = ox1 = oy2 = ox2 = 0.f; ar = 0.f; }  // inert
    spk4[tid] = make_float4(oy1, ox1, oy2, ox2);
    sarea[tid] = ar;
    sbox4[tid] = bx;
    sscr[tid] = sc; scl[tid] = c; sval[tid] = v;
  }
  __syncthreads();

  // ---- P2: overlap-bit matrix; thread = (row i, j-word), 64 IoUs each ----
  {
    int i = tid & 255, jw = tid >> 8;
    float4 me = spk4[i];
    float ma = sarea[i];
    int j0 = jw * 64;
    unsigned long long m = 0ULL;
#pragma unroll 8
    for (int jj = 0; jj < 64; jj++) {
      float4 ob = spk4[j0 + jj];
      float yy1 = fmaxf(me.x, ob.x), xx1 = fmaxf(me.y, ob.y);
      float yy2 = fminf(me.z, ob.z), xx2 = fminf(me.w, ob.w);
      float inter = fmaxf(yy2 - yy1, 0.f) * fmaxf(xx2 - xx1, 0.f);
      float uni = (ma + sarea[j0 + jj]) - inter;
      if (inter / fmaxf(uni, 1e-12f) > 0.3f) m |= 1ULL << jj;
    }
    smask[i][jw] = m;
  }
  __syncthreads();

  // ---- P3: wave 0 greedy resolve + parallel writes ----
  if (wv == 0) {
    unsigned long long m[4][4];
    int vv[4];
    for (int s = 0; s < 4; s++) {
      int i = s * 64 + lane;
      m[s][0] = smask[i][0]; m[s][1] = smask[i][1];
      m[s][2] = smask[i][2]; m[s][3] = smask[i][3];
      vv[s] = sval[i];
    }
    bool all_valid = ((__ballot(vv[0] != 0) & __ballot(vv[1] != 0) &
                       __ballot(vv[2] != 0) & __ballot(vv[3] != 0)) == ~0ULL);
    unsigned long long acc[4] = {0ULL, 0ULL, 0ULL, 0ULL};
    int kcount = 0;
    bool stop = false;
    for (int s = 0; s < 4 && !stop; s++) {
      bool ok = vv[s] && (((m[s][0] & acc[0]) | (m[s][1] & acc[1]) |
                           (m[s][2] & acc[2]) | (m[s][3] & acc[3])) == 0ULL);
      unsigned long long bal = __ballot(ok);
      while (bal) {
        int o = __ffsll((unsigned long long)bal) - 1;  // lowest index = greedy
        acc[s] |= 1ULL << o;
        kcount++;
        if (kcount == MAXI) { stop = true; break; }
        ok = ok && !((m[s][s] >> o) & 1ULL) && (lane != o);
        bal = __ballot(ok);
      }
    }
    int prefix[4], run = 0;
    for (int s = 0; s < 4; s++) { prefix[s] = run; run += (int)__popcll(acc[s]); }
    for (int s = 0; s < 4; s++) {
      if ((acc[s] >> lane) & 1ULL) {
        int i = s * 64 + lane;
        int row = prefix[s] + (int)__popcll(acc[s] & ((1ULL << lane) - 1ULL));
        float4 bx = sbox4[i];
        float* dr = det + ((size_t)b * MAXI + row) * 6;
        dr[0] = bx.x; dr[1] = bx.y; dr[2] = bx.z; dr[3] = bx.w;
        dr[4] = (float)scl[i]; dr[5] = sscr[i];
        kpk4[row] = spk4[i];
        karea[row] = sarea[i];
      }
    }
    if (lane == 0) {
      s_kcount = kcount;
      s_need = (kcount < MAXI && all_valid) ? 1 : 0;
    }
  }
  __syncthreads();

  // ---- P4: rare serial continuation past candidate 256 (wave 0) ----
  if (s_need && wv == 0) {
    int kept = s_kcount;
    float k0y1 = 0.f, k0x1 = 0.f, k0y2 = 0.f, k0x2 = 0.f, k0a = 0.f;
    float k1y1 = 0.f, k1x1 = 0.f, k1y2 = 0.f, k1x2 = 0.f, k1a = 0.f;
    if (lane < kept) {
      float4 t = kpk4[lane];
      k0y1 = t.x; k0x1 = t.y; k0y2 = t.z; k0x2 = t.w; k0a = karea[lane];
    }
    if (64 + lane < kept) {
      float4 t = kpk4[64 + lane];
      k1y1 = t.x; k1x1 = t.y; k1y2 = t.z; k1x2 = t.w; k1a = karea[64 + lane];
    }
    bool done = false;
    for (int base = 256; base < NN && !done; base += 64) {
      int pi = sperm[base + lane];
      int o = b * NPAD + pi;
      float4 bx = ((const float4*)box)[o];
      int lv = valid[o];
      int lc = cls[o];
      float lsc = score[o];
      int lim = (NN - base < 64) ? (NN - base) : 64;
      for (int j = 0; j < lim; j++) {
        int v = __shfl(lv, j, 64);
        if (!v) { done = true; break; }   // sorted: all invalid at the end
        float y1 = __shfl(bx.x, j, 64);
        float x1 = __shfl(bx.y, j, 64);
        float y2 = __shfl(bx.z, j, 64);
        float x2 = __shfl(bx.w, j, 64);
        int c = __shfl(lc, j, 64);
        float off = 2.0f * (float)c;
        float oy1 = y1 + off, ox1 = x1 + off, oy2 = y2 + off, ox2 = x2 + off;
        float area_i = (oy2 - oy1) * (ox2 - ox1);
        bool pred = false;
        if (lane < kept) {
          float yy1 = fmaxf(oy1, k0y1), xx1 = fmaxf(ox1, k0x1);
          float yy2 = fminf(oy2, k0y2), xx2 = fminf(ox2, k0x2);
          float inter = fmaxf(yy2 - yy1, 0.f) * fmaxf(xx2 - xx1, 0.f);
          float uni = (area_i + k0a) - inter;
          pred = (inter / fmaxf(uni, 1e-12f)) > 0.3f;
        }
        if (64 + lane < kept) {
          float yy1 = fmaxf(oy1, k1y1), xx1 = fmaxf(ox1, k1x1);
          float yy2 = fminf(oy2, k1y2), xx2 = fminf(ox2, k1x2);
          float inter = fmaxf(yy2 - yy1, 0.f) * fmaxf(xx2 - xx1, 0.f);
          float uni = (area_i + k1a) - inter;
          pred = pred || ((inter / fmaxf(uni, 1e-12f)) > 0.3f);
        }
        if (__ballot(pred) == 0ULL) {            // wave-uniform accept
          if (kept < 64) {
            if (lane == kept) { k0y1 = oy1; k0x1 = ox1; k0y2 = oy2; k0x2 = ox2; k0a = area_i; }
          } else {
            if (lane == kept - 64) { k1y1 = oy1; k1x1 = ox1; k1y2 = oy2; k1x2 = ox2; k1a = area_i; }
          }
          float sc = __shfl(lsc, j, 64);
          if (lane == 0) {
            float* dr = det + ((size_t)b * MAXI + kept) * 6;
            dr[0] = y1; dr[1] = x1; dr[2] = y2; dr[3] = x2;
            dr[4] = (float)c; dr[5] = sc;
          }
          kept++;
          if (kept == MAXI) { done = true; break; }
        }
      }
    }
    if (lane == 0) s_kcount = kept;
  }
  __syncthreads();

  // ---- zero-fill remaining det rows (d_out is poisoned 0xAA) ----
  {
    int kc = s_kcount;
    int rem = (MAXI - kc) * 6;
    float* dr0 = det + ((size_t)b * MAXI + kc) * 6;
    for (int t = tid; t < rem; t += 1024) dr0[t] = 0.f;
  }
}

// ---------------------------------------------------------------------------
// Kernel D: attention mask. One block per (batch, row); 256 threads,
// 2 pixels per thread; ballot+popcount compaction. [R4-proven bit-exact]
// ---------------------------------------------------------------------------
__global__ void k_mask(const float* __restrict__ det, float* __restrict__ mask) {
  __shared__ float lx1[MAXI], lx2[MAXI];
  __shared__ unsigned long long wmask[4];
  int x = blockIdx.x;
  int h = x & (HH - 1);
  int b = x >> 9;
  int tid = threadIdx.x;
  int wv = tid >> 6, ln = tid & 63;
  float ys = ((float)h + 0.5f) * (1.0f / 512.0f);
  bool inb = false;
  float bx1 = 0.f, bx2 = 0.f;
  if (tid < MAXI) {
    const float* dr = det + ((size_t)b * MAXI + tid) * 6;
    float y1 = dr[0], y2 = dr[2];
    bx1 = dr[1]; bx2 = dr[3];
    inb = (ys >= y1 && ys < y2);   // zero (padded) boxes cover nothing
  }
  unsigned long long bm = __ballot(inb);
  if (ln == 0) wmask[wv] = bm;
  __syncthreads();
  int n = __popcll(wmask[0]) + __popcll(wmask[1]);  // tid<100 only in waves 0,1
  if (inb) {
    int pos = (wv ? __popcll(wmask[0]) : 0) +
              __popcll(bm & ((1ULL << ln) - 1ULL));
    lx1[pos] = bx1; lx2[pos] = bx2;
  }
  __syncthreads();
  float xs0 = ((float)tid + 0.5f) * (1.0f / 512.0f);
  float xs1 = ((float)(tid + 256) + 0.5f) * (1.0f / 512.0f);
  bool c0 = false, c1 = false;
  for (int t = 0; t < n; t++) {
    float a = lx1[t], bq = lx2[t];
    c0 = c0 || (xs0 >= a && xs0 < bq);
    c1 = c1 || (xs1 >= a && xs1 < bq);
  }
  float* row = mask + ((size_t)b * HH + h) * WW;
  row[tid] = c0 ? 1.0f : 0.0f;
  row[tid + 256] = c1 ? 1.0f : 0.0f;
}

// ---------------------------------------------------------------------------
extern "C" void kernel_launch(void* const* d_in, const int* in_sizes, int n_in,
                              void* d_out, int out_size, void* d_ws, size_t ws_size,
                              hipStream_t stream) {
  const float* rois = (const float*)d_in[0];
  const float* probs = (const float*)d_in[1];
  const float* deltas = (const float*)d_in[2];
  const float* stdv = (const float*)d_in[3];
  float* out = (float*)d_out;
  float* det = out;                  // [8,100,6] = 4800 floats
  float* mask = out + BB * MAXI * 6; // [8,512,512]

  char* p = (char*)d_ws;
  unsigned long long* gkeys = (unsigned long long*)p; p += (size_t)BB * NPAD * 8;
  float* box     = (float*)p; p += (size_t)BB * NPAD * 16;
  float* score   = (float*)p; p += (size_t)BB * NPAD * 4;
  int*   cls     = (int*)p;   p += (size_t)BB * NPAD * 4;
  int*   valid   = (int*)p;   p += (size_t)BB * NPAD * 4;
  int*   partial = (int*)p;   p += (size_t)BB * 8 * NPAD * 4;

  k_refine<<<(BB * NPAD) / 4, 256, 0, stream>>>(rois, probs, deltas, stdv,
                                                score, cls, valid, box, gkeys);
  k_rankp<<<BB * 64, 256, 0, stream>>>(gkeys, partial);
  k_permnms<<<BB, 1024, 0, stream>>>(partial, score, cls, valid, box, det);
  k_mask<<<BB * HH, 256, 0, stream>>>(det, mask);
}

// Round 10
// 123.500 us; speedup vs baseline: 1.3219x; 1.0003x over previous
//
#include <hip/hip_runtime.h>
#include <math.h>

#define BB 8
#define NN 2000
#define CC 81
#define NPAD 2048
#define MAXI 100
#define HH 512
#define WW 512

// ---------------------------------------------------------------------------
// Kernel A: per-proposal class argmax, delta refine, validity, sort key.
// [R4-proven bit-exact]
// ---------------------------------------------------------------------------
__global__ void k_refine(const float* __restrict__ rois,
                         const float* __restrict__ probs,
                         const float* __restrict__ deltas,
                         const float* __restrict__ stdv,
                         float* __restrict__ score, int* __restrict__ cls,
                         int* __restrict__ valid, float* __restrict__ box,
                         unsigned long long* __restrict__ gkeys) {
#pragma clang fp contract(off)
  int g = blockIdx.x * 4 + (threadIdx.x >> 6);
  if (g >= BB * NPAD) return;
  int lane = threadIdx.x & 63;
  int b = g >> 11, n = g & (NPAD - 1);
  if (n >= NN) {                      // pad slot: sentinel key + invalid
    if (lane == 0) {
      unsigned u = __float_as_uint(-INFINITY);
      u = ~u;                         // sign set -> ~u
      gkeys[b * NPAD + n] =
          ((unsigned long long)u << 32) | (0xFFFFFFFFu - (unsigned)n);
      valid[b * NPAD + n] = 0;        // NMS gathers this slot; ws is poisoned
    }
    return;
  }
  const float* pp = probs + ((size_t)b * NN + n) * CC;
  float best = -INFINITY;
  int bc = CC;
  for (int c = lane; c < CC; c += 64) {
    float p = pp[c];
    if (p > best) { best = p; bc = c; }   // per-lane stride keeps first max
  }
  // cross-lane argmax, first-occurrence tie-break (smaller class wins)
  for (int off = 32; off; off >>= 1) {
    float ob = __shfl_xor(best, off, 64);
    int oc = __shfl_xor(bc, off, 64);
    if (ob > best || (ob == best && oc < bc)) { best = ob; bc = oc; }
  }
  if (lane == 0) {
    int idx = b * NPAD + n;
    const float* r = rois + ((size_t)b * NN + n) * 4;
    const float* dd = deltas + (((size_t)b * NN + n) * CC + bc) * 4;
    float d0 = dd[0] * stdv[0], d1 = dd[1] * stdv[1];
    float d2 = dd[2] * stdv[2], d3 = dd[3] * stdv[3];
    float y1 = r[0], x1 = r[1], y2 = r[2], x2 = r[3];
    float h = y2 - y1, w = x2 - x1;
    float cy = y1 + 0.5f * h + d0 * h;
    float cx = x1 + 0.5f * w + d1 * w;
    h = h * (float)exp((double)d2);   // double path ~= correctly-rounded f32 exp
    w = w * (float)exp((double)d3);
    float ny1 = cy - 0.5f * h, nx1 = cx - 0.5f * w;
    float ny2 = cy + 0.5f * h, nx2 = cx + 0.5f * w;
    ny1 = fminf(fmaxf(ny1, 0.f), 1.f);
    nx1 = fminf(fmaxf(nx1, 0.f), 1.f);
    ny2 = fminf(fmaxf(ny2, 0.f), 1.f);
    nx2 = fminf(fmaxf(nx2, 0.f), 1.f);
    box[idx * 4 + 0] = ny1;
    box[idx * 4 + 1] = nx1;
    box[idx * 4 + 2] = ny2;
    box[idx * 4 + 3] = nx2;
    score[idx] = best;
    cls[idx] = bc;
    int v = (bc > 0 && best >= 0.05f) ? 1 : 0;
    valid[idx] = v;
    float ks = v ? best : -INFINITY;
    unsigned u = __float_as_uint(ks);
    u = (u & 0x80000000u) ? ~u : (u | 0x80000000u);
    gkeys[idx] = ((unsigned long long)u << 32) | (0xFFFFFFFFu - (unsigned)n);
  }
}

// ---------------------------------------------------------------------------
// Kernel B: partial rank counts, CHIP-WIDE (512 blocks). [R4-proven]
// ---------------------------------------------------------------------------
__global__ void k_rankp(const unsigned long long* __restrict__ gkeys,
                        int* __restrict__ partial) {
  __shared__ unsigned long long sk[256];
  int blk = blockIdx.x;                 // b*64 + ip*8 + jp
  int jp = blk & 7, ip = (blk >> 3) & 7, b = blk >> 6;
  int tid = threadIdx.x;
  sk[tid] = gkeys[b * NPAD + jp * 256 + tid];
  unsigned long long myk = gkeys[b * NPAD + ip * 256 + tid];
  __syncthreads();
  int cnt = 0;
#pragma unroll 8
  for (int j = 0; j < 256; j++) cnt += (sk[j] > myk) ? 1 : 0;
  partial[(b * 8 + jp) * NPAD + ip * 256 + tid] = cnt;
}

// ---------------------------------------------------------------------------
// Kernel C (v9): perm + mask-resolve NMS, 1 block of 1024 threads per batch.
//   P0+P1 fused: the thread computing rank[e] stages candidate e directly
//     when rank<256 (removes a barrier + a scattered-gather round vs R9).
//   P2: STRICTLY-LOWER-TRIANGLE overlap bits. Greedy accepts the lowest
//     surviving index, so bits j>=i are never read by the resolve
//     (within-word: survivors have lane>o; cross-word: later acc words are
//     zero). 6/16 waves skip entirely, 4 run half -> ~0.62x build cost.
//   P3: wave 0 greedy resolve, one ballot per accept; parallel det/kept
//     writes via popcount-prefix ranks. [R9-proven]
//   P4: rare serial continuation past candidate 256 (R7-proven loop).
// Same fp-contract-off IoU bits, union order, greedy order as reference.
// ---------------------------------------------------------------------------
__global__ void __launch_bounds__(1024)
k_permnms(const int* __restrict__ partial, const float* __restrict__ score,
          const int* __restrict__ cls, const int* __restrict__ valid,
          const float* __restrict__ box, float* __restrict__ det) {
#pragma clang fp contract(off)
  __shared__ int sperm[NPAD];
  __shared__ float4 spk4[256];      // offset box (oy1,ox1,oy2,ox2)
  __shared__ float sarea[256];
  __shared__ float4 sbox4[256];     // unoffset box (for det output)
  __shared__ float sscr[256];
  __shared__ int   scl[256];
  __shared__ int   sval[256];
  __shared__ unsigned long long smask[256][5];  // 4 words + pad
  __shared__ float4 kpk4[MAXI];     // kept offset boxes
  __shared__ float  karea[MAXI];
  __shared__ int s_kcount, s_need;

  int b = blockIdx.x, tid = threadIdx.x;
  int lane = tid & 63, wv = tid >> 6;

  if (tid == 0) { s_kcount = 0; s_need = 0; }
  // ---- P0+P1: rank-sum -> sperm; stage top-256 inline ----
  for (int e = tid; e < NPAD; e += 1024) {
    int rank = 0;
#pragma unroll
    for (int jp = 0; jp < 8; jp++) rank += partial[(b * 8 + jp) * NPAD + e];
    sperm[rank] = e;
    if (rank < 256) {
      int o = b * NPAD + e;
      float4 bx = ((const float4*)box)[o];
      int c = cls[o], v = valid[o];
      float sc = score[o];
      float off = 2.0f * (float)c;
      float oy1 = bx.x + off, ox1 = bx.y + off;
      float oy2 = bx.z + off, ox2 = bx.w + off;
      float ar = (oy2 - oy1) * (ox2 - ox1);
      if (!v) { oy1 = ox1 = oy2 = ox2 = 0.f; ar = 0.f; }  // inert
      spk4[rank] = make_float4(oy1, ox1, oy2, ox2);
      sarea[rank] = ar;
      sbox4[rank] = bx;
      sscr[rank] = sc; scl[rank] = c; sval[rank] = v;
    }
  }
  __syncthreads();

  // ---- P2: lower-triangle overlap bits; thread = (row i, j-word) ----
  {
    int i = tid & 255, jw = tid >> 8;
    int iw = i >> 6;
    unsigned long long m = 0ULL;
    if (jw <= iw) {                       // waves with jw>iw skip entirely
      float4 me = spk4[i];
      float ma = sarea[i];
      int j0 = jw * 64;
      int lim = (jw < iw) ? 64 : (i & 63);  // strictly j < i
#pragma unroll 4
      for (int jj = 0; jj < lim; jj++) {
        float4 ob = spk4[j0 + jj];
        float yy1 = fmaxf(me.x, ob.x), xx1 = fmaxf(me.y, ob.y);
        float yy2 = fminf(me.z, ob.z), xx2 = fminf(me.w, ob.w);
        float inter = fmaxf(yy2 - yy1, 0.f) * fmaxf(xx2 - xx1, 0.f);
        float uni = (ma + sarea[j0 + jj]) - inter;
        if (inter / fmaxf(uni, 1e-12f) > 0.3f) m |= 1ULL << jj;
      }
    }
    smask[i][jw] = m;
  }
  __syncthreads();

  // ---- P3: wave 0 greedy resolve + parallel writes ----
  if (wv == 0) {
    unsigned long long m[4][4];
    int vv[4];
    for (int s = 0; s < 4; s++) {
      int i = s * 64 + lane;
      m[s][0] = smask[i][0]; m[s][1] = smask[i][1];
      m[s][2] = smask[i][2]; m[s][3] = smask[i][3];
      vv[s] = sval[i];
    }
    bool all_valid = ((__ballot(vv[0] != 0) & __ballot(vv[1] != 0) &
                       __ballot(vv[2] != 0) & __ballot(vv[3] != 0)) == ~0ULL);
    unsigned long long acc[4] = {0ULL, 0ULL, 0ULL, 0ULL};
    int kcount = 0;
    bool stop = false;
    for (int s = 0; s < 4 && !stop; s++) {
      bool ok = vv[s] && (((m[s][0] & acc[0]) | (m[s][1] & acc[1]) |
                           (m[s][2] & acc[2]) | (m[s][3] & acc[3])) == 0ULL);
      unsigned long long bal = __ballot(ok);
      while (bal) {
        int o = __ffsll((unsigned long long)bal) - 1;  // lowest index = greedy
        acc[s] |= 1ULL << o;
        kcount++;
        if (kcount == MAXI) { stop = true; break; }
        ok = ok && !((m[s][s] >> o) & 1ULL) && (lane != o);
        bal = __ballot(ok);
      }
    }
    int prefix[4], run = 0;
    for (int s = 0; s < 4; s++) { prefix[s] = run; run += (int)__popcll(acc[s]); }
    for (int s = 0; s < 4; s++) {
      if ((acc[s] >> lane) & 1ULL) {
        int i = s * 64 + lane;
        int row = prefix[s] + (int)__popcll(acc[s] & ((1ULL << lane) - 1ULL));
        float4 bx = sbox4[i];
        float* dr = det + ((size_t)b * MAXI + row) * 6;
        dr[0] = bx.x; dr[1] = bx.y; dr[2] = bx.z; dr[3] = bx.w;
        dr[4] = (float)scl[i]; dr[5] = sscr[i];
        kpk4[row] = spk4[i];
        karea[row] = sarea[i];
      }
    }
    if (lane == 0) {
      s_kcount = kcount;
      s_need = (kcount < MAXI && all_valid) ? 1 : 0;
    }
  }
  __syncthreads();

  // ---- P4: rare serial continuation past candidate 256 (wave 0) ----
  if (s_need && wv == 0) {
    int kept = s_kcount;
    float k0y1 = 0.f, k0x1 = 0.f, k0y2 = 0.f, k0x2 = 0.f, k0a = 0.f;
    float k1y1 = 0.f, k1x1 = 0.f, k1y2 = 0.f, k1x2 = 0.f, k1a = 0.f;
    if (lane < kept) {
      float4 t = kpk4[lane];
      k0y1 = t.x; k0x1 = t.y; k0y2 = t.z; k0x2 = t.w; k0a = karea[lane];
    }
    if (64 + lane < kept) {
      float4 t = kpk4[64 + lane];
      k1y1 = t.x; k1x1 = t.y; k1y2 = t.z; k1x2 = t.w; k1a = karea[64 + lane];
    }
    bool done = false;
    for (int base = 256; base < NN && !done; base += 64) {
      int pi = sperm[base + lane];
      int o = b * NPAD + pi;
      float4 bx = ((const float4*)box)[o];
      int lv = valid[o];
      int lc = cls[o];
      float lsc = score[o];
      int lim = (NN - base < 64) ? (NN - base) : 64;
      for (int j = 0; j < lim; j++) {
        int v = __shfl(lv, j, 64);
        if (!v) { done = true; break; }   // sorted: all invalid at the end
        float y1 = __shfl(bx.x, j, 64);
        float x1 = __shfl(bx.y, j, 64);
        float y2 = __shfl(bx.z, j, 64);
        float x2 = __shfl(bx.w, j, 64);
        int c = __shfl(lc, j, 64);
        float off = 2.0f * (float)c;
        float oy1 = y1 + off, ox1 = x1 + off, oy2 = y2 + off, ox2 = x2 + off;
        float area_i = (oy2 - oy1) * (ox2 - ox1);
        bool pred = false;
        if (lane < kept) {
          float yy1 = fmaxf(oy1, k0y1), xx1 = fmaxf(ox1, k0x1);
          float yy2 = fminf(oy2, k0y2), xx2 = fminf(ox2, k0x2);
          float inter = fmaxf(yy2 - yy1, 0.f) * fmaxf(xx2 - xx1, 0.f);
          float uni = (area_i + k0a) - inter;
          pred = (inter / fmaxf(uni, 1e-12f)) > 0.3f;
        }
        if (64 + lane < kept) {
          float yy1 = fmaxf(oy1, k1y1), xx1 = fmaxf(ox1, k1x1);
          float yy2 = fminf(oy2, k1y2), xx2 = fminf(ox2, k1x2);
          float inter = fmaxf(yy2 - yy1, 0.f) * fmaxf(xx2 - xx1, 0.f);
          float uni = (area_i + k1a) - inter;
          pred = pred || ((inter / fmaxf(uni, 1e-12f)) > 0.3f);
        }
        if (__ballot(pred) == 0ULL) {            // wave-uniform accept
          if (kept < 64) {
            if (lane == kept) { k0y1 = oy1; k0x1 = ox1; k0y2 = oy2; k0x2 = ox2; k0a = area_i; }
          } else {
            if (lane == kept - 64) { k1y1 = oy1; k1x1 = ox1; k1y2 = oy2; k1x2 = ox2; k1a = area_i; }
          }
          float sc = __shfl(lsc, j, 64);
          if (lane == 0) {
            float* dr = det + ((size_t)b * MAXI + kept) * 6;
            dr[0] = y1; dr[1] = x1; dr[2] = y2; dr[3] = x2;
            dr[4] = (float)c; dr[5] = sc;
          }
          kept++;
          if (kept == MAXI) { done = true; break; }
        }
      }
    }
    if (lane == 0) s_kcount = kept;
  }
  __syncthreads();

  // ---- zero-fill remaining det rows (d_out is poisoned 0xAA) ----
  {
    int kc = s_kcount;
    int rem = (MAXI - kc) * 6;
    float* dr0 = det + ((size_t)b * MAXI + kc) * 6;
    for (int t = tid; t < rem; t += 1024) dr0[t] = 0.f;
  }
}

// ---------------------------------------------------------------------------
// Kernel D: attention mask. One block per (batch, row); 256 threads,
// 2 pixels per thread; ballot+popcount compaction. [R4-proven bit-exact]
// ---------------------------------------------------------------------------
__global__ void k_mask(const float* __restrict__ det, float* __restrict__ mask) {
  __shared__ float lx1[MAXI], lx2[MAXI];
  __shared__ unsigned long long wmask[4];
  int x = blockIdx.x;
  int h = x & (HH - 1);
  int b = x >> 9;
  int tid = threadIdx.x;
  int wv = tid >> 6, ln = tid & 63;
  float ys = ((float)h + 0.5f) * (1.0f / 512.0f);
  bool inb = false;
  float bx1 = 0.f, bx2 = 0.f;
  if (tid < MAXI) {
    const float* dr = det + ((size_t)b * MAXI + tid) * 6;
    float y1 = dr[0], y2 = dr[2];
    bx1 = dr[1]; bx2 = dr[3];
    inb = (ys >= y1 && ys < y2);   // zero (padded) boxes cover nothing
  }
  unsigned long long bm = __ballot(inb);
  if (ln == 0) wmask[wv] = bm;
  __syncthreads();
  int n = __popcll(wmask[0]) + __popcll(wmask[1]);  // tid<100 only in waves 0,1
  if (inb) {
    int pos = (wv ? __popcll(wmask[0]) : 0) +
              __popcll(bm & ((1ULL << ln) - 1ULL));
    lx1[pos] = bx1; lx2[pos] = bx2;
  }
  __syncthreads();
  float xs0 = ((float)tid + 0.5f) * (1.0f / 512.0f);
  float xs1 = ((float)(tid + 256) + 0.5f) * (1.0f / 512.0f);
  bool c0 = false, c1 = false;
  for (int t = 0; t < n; t++) {
    float a = lx1[t], bq = lx2[t];
    c0 = c0 || (xs0 >= a && xs0 < bq);
    c1 = c1 || (xs1 >= a && xs1 < bq);
  }
  float* row = mask + ((size_t)b * HH + h) * WW;
  row[tid] = c0 ? 1.0f : 0.0f;
  row[tid + 256] = c1 ? 1.0f : 0.0f;
}

// ---------------------------------------------------------------------------
extern "C" void kernel_launch(void* const* d_in, const int* in_sizes, int n_in,
                              void* d_out, int out_size, void* d_ws, size_t ws_size,
                              hipStream_t stream) {
  const float* rois = (const float*)d_in[0];
  const float* probs = (const float*)d_in[1];
  const float* deltas = (const float*)d_in[2];
  const float* stdv = (const float*)d_in[3];
  float* out = (float*)d_out;
  float* det = out;                  // [8,100,6] = 4800 floats
  float* mask = out + BB * MAXI * 6; // [8,512,512]

  char* p = (char*)d_ws;
  unsigned long long* gkeys = (unsigned long long*)p; p += (size_t)BB * NPAD * 8;
  float* box     = (float*)p; p += (size_t)BB * NPAD * 16;
  float* score   = (float*)p; p += (size_t)BB * NPAD * 4;
  int*   cls     = (int*)p;   p += (size_t)BB * NPAD * 4;
  int*   valid   = (int*)p;   p += (size_t)BB * NPAD * 4;
  int*   partial = (int*)p;   p += (size_t)BB * 8 * NPAD * 4;

  k_refine<<<(BB * NPAD) / 4, 256, 0, stream>>>(rois, probs, deltas, stdv,
                                                score, cls, valid, box, gkeys);
  k_rankp<<<BB * 64, 256, 0, stream>>>(gkeys, partial);
  k_permnms<<<BB, 1024, 0, stream>>>(partial, score, cls, valid, box, det);
  k_mask<<<BB * HH, 256, 0, stream>>>(det, mask);
}